// Round 1
// baseline (15065.767 us; speedup 1.0000x reference)
//
#include <hip/hip_runtime.h>
#include <hip/hip_runtime_api.h>
#include <cstdint>
#include <cstddef>

// ---------------------------------------------------------------------------
// Sparse 3D CNN stage: 6x (sparse conv 3^3 + BN + ReLU), 2x stride-2 maxpool,
// global max pool, 3x FC.  Round 1: fp32 everywhere, correctness-first.
// ---------------------------------------------------------------------------

#define CMID 512

// ---- sparse conv: gather-GEMM-scatter over 27 kernel offsets --------------
// grid: (ceil(P/64), C_out/64, 27), block 256.  64x64 tile, 4x4 per thread.
// Padded pairs have out_idx == n_out (sentinel) -> tile early-exit / masked
// scatter.  Within one offset k the out rows are unique; across k we use
// atomicAdd (device scope).
__global__ __launch_bounds__(256) void conv_gemm(
    const float* __restrict__ x, const float* __restrict__ W,
    const int* __restrict__ in_map, const int* __restrict__ out_map,
    float* __restrict__ out, int P, int n_out, int C_in)
{
  const int C_out = CMID;
  const int k  = blockIdx.z;
  const int p0 = blockIdx.x * 64;
  const int j0 = blockIdx.y * 64;
  const int t  = threadIdx.x;

  __shared__ int out_s[64];
  __shared__ int in_s[64];
  __shared__ int any_valid;
  if (t == 0) any_valid = 0;
  __syncthreads();
  if (t < 64) {
    int p  = p0 + t;
    int oi = (p < P) ? out_map[(size_t)k * P + p] : n_out;
    int ii = (p < P) ? in_map[(size_t)k * P + p]  : 0;
    out_s[t] = oi;
    in_s[t]  = ii;
    if (oi < n_out) any_valid = 1;   // benign race, all write 1
  }
  __syncthreads();
  if (!any_valid) return;            // block-uniform

  __shared__ float A_s[16][68];      // [kk][pair], padded pitch vs conflicts
  __shared__ float B_s[16][68];      // [kk][cout]

  float acc[4][4] = {{0.f}};
  const int ty = t >> 4;             // 0..15 -> pair group (rows ty*4..+3)
  const int tx = t & 15;             // 0..15 -> cout group (cols tx*4..+3)
  const int lp = t >> 2;             // A-loader pair 0..63
  const int lk = (t & 3) * 4;        // A-loader k offset

  const float* Wk   = W + (size_t)k * C_in * C_out + j0;
  const float* xrow = x + (size_t)in_s[lp] * C_in + lk;

  for (int kb = 0; kb < C_in; kb += 16) {
    float4 av = *(const float4*)(xrow + kb);
    A_s[lk + 0][lp] = av.x;
    A_s[lk + 1][lp] = av.y;
    A_s[lk + 2][lp] = av.z;
    A_s[lk + 3][lp] = av.w;
    float4 bv = *(const float4*)(Wk + (size_t)(kb + ty) * C_out + tx * 4);
    *(float4*)&B_s[ty][tx * 4] = bv;
    __syncthreads();
#pragma unroll
    for (int kk = 0; kk < 16; ++kk) {
      float4 a = *(const float4*)&A_s[kk][ty * 4];
      float4 b = *(const float4*)&B_s[kk][tx * 4];
      acc[0][0] += a.x * b.x; acc[0][1] += a.x * b.y; acc[0][2] += a.x * b.z; acc[0][3] += a.x * b.w;
      acc[1][0] += a.y * b.x; acc[1][1] += a.y * b.y; acc[1][2] += a.y * b.z; acc[1][3] += a.y * b.w;
      acc[2][0] += a.z * b.x; acc[2][1] += a.z * b.y; acc[2][2] += a.z * b.z; acc[2][3] += a.z * b.w;
      acc[3][0] += a.w * b.x; acc[3][1] += a.w * b.y; acc[3][2] += a.w * b.z; acc[3][3] += a.w * b.w;
    }
    __syncthreads();
  }

#pragma unroll
  for (int i = 0; i < 4; ++i) {
    int o = out_s[ty * 4 + i];
    if (o < n_out) {
      float* orow = out + (size_t)o * C_out + j0 + tx * 4;
      atomicAdd(orow + 0, acc[i][0]);
      atomicAdd(orow + 1, acc[i][1]);
      atomicAdd(orow + 2, acc[i][2]);
      atomicAdd(orow + 3, acc[i][3]);
    }
  }
}

// ---- BN (training-mode, biased var) stats: per-channel sum / sumsq --------
// block 256: thread owns channels t and t+256, rows strided by grid.
__global__ __launch_bounds__(256) void bn_stats_kernel(
    const float* __restrict__ x, float* __restrict__ stats, int n)
{
  int t = threadIdx.x;
  float s0 = 0.f, q0 = 0.f, s1 = 0.f, q1 = 0.f;
  for (int r = blockIdx.x; r < n; r += gridDim.x) {
    const float* row = x + (size_t)r * CMID;
    float v0 = row[t];
    float v1 = row[t + 256];
    s0 += v0; q0 += v0 * v0;
    s1 += v1; q1 += v1 * v1;
  }
  atomicAdd(&stats[t],        s0);
  atomicAdd(&stats[512 + t],  q0);
  atomicAdd(&stats[t + 256],  s1);
  atomicAdd(&stats[768 + t],  q1);
}

// ---- BN apply + ReLU (in place) -------------------------------------------
__global__ __launch_bounds__(256) void bn_apply_kernel(
    float* __restrict__ x, const float* __restrict__ stats,
    const float* __restrict__ gamma, const float* __restrict__ beta,
    long total, float inv_n)
{
  long i = (long)blockIdx.x * 256 + threadIdx.x;
  if (i >= total) return;
  int c = (int)(i & 511);
  float mu  = stats[c] * inv_n;
  float var = stats[512 + c] * inv_n - mu * mu;
  float g   = gamma[c] * rsqrtf(var + 1e-5f);
  float v   = (x[i] - mu) * g + beta[c];
  x[i] = v > 0.f ? v : 0.f;
}

// ---- segment max pool (values are post-ReLU >= 0: int-punned atomicMax) ---
__global__ __launch_bounds__(256) void pool_max_kernel(
    const float* __restrict__ x, const int* __restrict__ idx,
    float* __restrict__ out, long total)
{
  long i = (long)blockIdx.x * 256 + threadIdx.x;
  if (i >= total) return;
  int r = (int)(i >> 9);
  int c = (int)(i & 511);
  int o = idx[r];
  atomicMax((int*)(out + (size_t)o * CMID + c), __float_as_int(x[i]));
}

// ---- FC layer: out[8][N] = relu?(x[8][K] @ W[K][N] + b) -------------------
// block 256, grid N/256; x staged in LDS (broadcast reads), W coalesced rows.
__global__ __launch_bounds__(256) void fc_kernel(
    const float* __restrict__ x, const float* __restrict__ W,
    const float* __restrict__ bias, float* __restrict__ out,
    int K, int N, int relu)
{
  __shared__ float xs[8][512];
  int t = threadIdx.x;
  int j = blockIdx.x * 256 + t;
  float acc[8] = {0.f, 0.f, 0.f, 0.f, 0.f, 0.f, 0.f, 0.f};
  for (int kb = 0; kb < K; kb += 512) {
    for (int i = t; i < 8 * 512; i += 256) {
      int b  = i >> 9;
      int kk = i & 511;
      xs[b][kk] = x[(size_t)b * K + kb + kk];
    }
    __syncthreads();
#pragma unroll 8
    for (int kk = 0; kk < 512; ++kk) {
      float wv = W[(size_t)(kb + kk) * N + j];
#pragma unroll
      for (int b = 0; b < 8; ++b) acc[b] += xs[b][kk] * wv;
    }
    __syncthreads();
  }
  float bv = bias[j];
#pragma unroll
  for (int b = 0; b < 8; ++b) {
    float v = acc[b] + bv;
    if (relu) v = v > 0.f ? v : 0.f;
    out[(size_t)b * N + j] = v;
  }
}

// ---- FC3: [8,4096] @ [4096,40] + b, K-split with atomic accumulate --------
__global__ __launch_bounds__(320) void fc3_kernel(
    const float* __restrict__ x, const float* __restrict__ W,
    const float* __restrict__ bias, float* __restrict__ out)
{
  int t = threadIdx.x;           // 0..319
  int j = t % 40;
  int b = t / 40;
  int kb = blockIdx.x * 128;     // 32 chunks x 128
  float acc = 0.f;
#pragma unroll 8
  for (int kk = 0; kk < 128; ++kk) {
    acc += x[(size_t)b * 4096 + kb + kk] * W[(size_t)(kb + kk) * 40 + j];
  }
  if (blockIdx.x == 0) acc += bias[j];
  atomicAdd(&out[(size_t)b * 40 + j], acc);
}

// ---------------------------------------------------------------------------
extern "C" void kernel_launch(void* const* d_in, const int* in_sizes, int n_in,
                              void* d_out, int out_size, void* d_ws, size_t ws_size,
                              hipStream_t stream)
{
  const float* feats  = (const float*)d_in[0];
  const float* w1     = (const float*)d_in[1];
  const float* w2     = (const float*)d_in[2];
  const float* w3     = (const float*)d_in[3];
  const float* w4     = (const float*)d_in[4];
  const float* w5     = (const float*)d_in[5];
  const float* w6     = (const float*)d_in[6];
  const float* bn_g   = (const float*)d_in[7];   // [6][512]
  const float* bn_b   = (const float*)d_in[8];
  const float* fc1_w  = (const float*)d_in[9];
  const float* fc1_b  = (const float*)d_in[10];
  const float* fc2_w  = (const float*)d_in[11];
  const float* fc2_b  = (const float*)d_in[12];
  const float* fc3_w  = (const float*)d_in[13];
  const float* fc3_b  = (const float*)d_in[14];
  const int* map1_in  = (const int*)d_in[15];
  const int* map1_out = (const int*)d_in[16];
  const int* map2_in  = (const int*)d_in[17];
  const int* map2_out = (const int*)d_in[18];
  const int* pool1_idx = (const int*)d_in[19];
  const int* pool2_idx = (const int*)d_in[20];
  const int* batch_idx = (const int*)d_in[21];

  const int N1 = in_sizes[0] / 256;     // 32768
  const int P1 = in_sizes[15] / 27;     // padded pairs, level 1
  const int P2 = in_sizes[17] / 27;     // padded pairs, level 2
  const int n2 = in_sizes[20];          // pool2_idx has n2 entries
  const int n3 = in_sizes[21];          // batch_idx has n3 entries

  // workspace layout (fp32): two ping-pong feature buffers + BN stats
  const size_t bufBytes = (size_t)N1 * CMID * sizeof(float);   // 64 MiB
  float* bufA  = (float*)d_ws;
  float* bufB  = (float*)((char*)d_ws + bufBytes);
  float* stats = (float*)((char*)d_ws + 2 * bufBytes);
  // FC scratch reuses bufA after conv phase is done:
  float* pooled = bufA;                // [8][512]
  float* h1     = bufA + 8 * 512;      // [8][4096]
  float* h2     = h1 + 8 * 4096;       // [8][4096]

  const dim3 cgrid1((P1 + 63) / 64, CMID / 64, 27);
  const dim3 cgrid2((P2 + 63) / 64, CMID / 64, 27);
  const long tot1 = (long)N1 * CMID;
  const long tot2 = (long)n2 * CMID;
  const long tot3 = (long)n3 * CMID;

  auto bn = [&](float* buf, int layer, int n, long tot) {
    hipMemsetAsync(stats, 0, 1024 * sizeof(float), stream);
    bn_stats_kernel<<<256, 256, 0, stream>>>(buf, stats, n);
    bn_apply_kernel<<<(int)((tot + 255) / 256), 256, 0, stream>>>(
        buf, stats, bn_g + layer * CMID, bn_b + layer * CMID, tot, 1.0f / n);
  };

  // --- level-1 convs (N1 sites) ---
  hipMemsetAsync(bufA, 0, bufBytes, stream);
  conv_gemm<<<cgrid1, 256, 0, stream>>>(feats, w1, map1_in, map1_out, bufA, P1, N1, 256);
  bn(bufA, 0, N1, tot1);

  hipMemsetAsync(bufB, 0, bufBytes, stream);
  conv_gemm<<<cgrid1, 256, 0, stream>>>(bufA, w2, map1_in, map1_out, bufB, P1, N1, 512);
  bn(bufB, 1, N1, tot1);

  hipMemsetAsync(bufA, 0, bufBytes, stream);
  conv_gemm<<<cgrid1, 256, 0, stream>>>(bufB, w3, map1_in, map1_out, bufA, P1, N1, 512);
  bn(bufA, 2, N1, tot1);

  // --- pool 1: N1 -> n2 ---
  hipMemsetAsync(bufB, 0, (size_t)n2 * CMID * sizeof(float), stream);
  pool_max_kernel<<<(int)((tot1 + 255) / 256), 256, 0, stream>>>(bufA, pool1_idx, bufB, tot1);

  // --- level-2 convs (n2 sites) ---
  hipMemsetAsync(bufA, 0, (size_t)n2 * CMID * sizeof(float), stream);
  conv_gemm<<<cgrid2, 256, 0, stream>>>(bufB, w4, map2_in, map2_out, bufA, P2, n2, 512);
  bn(bufA, 3, n2, tot2);

  hipMemsetAsync(bufB, 0, (size_t)n2 * CMID * sizeof(float), stream);
  conv_gemm<<<cgrid2, 256, 0, stream>>>(bufA, w5, map2_in, map2_out, bufB, P2, n2, 512);
  bn(bufB, 4, n2, tot2);

  hipMemsetAsync(bufA, 0, (size_t)n2 * CMID * sizeof(float), stream);
  conv_gemm<<<cgrid2, 256, 0, stream>>>(bufB, w6, map2_in, map2_out, bufA, P2, n2, 512);
  bn(bufA, 5, n2, tot2);

  // --- pool 2: n2 -> n3 ---
  hipMemsetAsync(bufB, 0, (size_t)n3 * CMID * sizeof(float), stream);
  pool_max_kernel<<<(int)((tot2 + 255) / 256), 256, 0, stream>>>(bufA, pool2_idx, bufB, tot2);

  // --- global max pool: n3 -> [8][512] (pooled aliases bufA; safe: bufA
  // feature data no longer needed, pooled written before fc1 reads it) ---
  hipMemsetAsync(pooled, 0, 8 * CMID * sizeof(float), stream);
  pool_max_kernel<<<(int)((tot3 + 255) / 256), 256, 0, stream>>>(bufB, batch_idx, pooled, tot3);

  // --- FC head ---
  fc_kernel<<<4096 / 256, 256, 0, stream>>>(pooled, fc1_w, fc1_b, h1, 512, 4096, 1);
  fc_kernel<<<4096 / 256, 256, 0, stream>>>(h1, fc2_w, fc2_b, h2, 4096, 4096, 1);
  hipMemsetAsync(d_out, 0, (size_t)out_size * sizeof(float), stream);
  fc3_kernel<<<32, 320, 0, stream>>>(h2, fc3_w, fc3_b, (float*)d_out);
}

// Round 2
// 3233.295 us; speedup vs baseline: 4.6596x; 4.6596x over previous
//
#include <hip/hip_runtime.h>
#include <cstdint>
#include <cstddef>

#define CMID 512

typedef __bf16 bf16x8 __attribute__((ext_vector_type(8)));
typedef float  f32x4  __attribute__((ext_vector_type(4)));

__device__ __forceinline__ ushort f2bf(float v) {
  unsigned u = __float_as_uint(v);
  unsigned r = (u + 0x7fffu + ((u >> 16) & 1u)) >> 16;   // RNE
  return (ushort)r;
}

// ---- W [27][Cin][512] f32  ->  wT [27][512][Cin] bf16 ----------------------
__global__ __launch_bounds__(256) void transpose_w_kernel(
    const float* __restrict__ W, ushort* __restrict__ wT, int Cin)
{
  __shared__ float tile[32][33];
  int k = blockIdx.z;
  int ci0 = blockIdx.x * 32, co0 = blockIdx.y * 32;
  int tx = threadIdx.x & 31, ty = threadIdx.x >> 5;
  const float* src = W + ((size_t)k * Cin + ci0) * CMID + co0;
  for (int r = ty; r < 32; r += 8)
    tile[r][tx] = src[(size_t)r * CMID + tx];
  __syncthreads();
  ushort* dst = wT + ((size_t)k * CMID + co0) * Cin + ci0;
  for (int r = ty; r < 32; r += 8)
    dst[(size_t)r * Cin + tx] = f2bf(tile[tx][r]);
}

// ---- sparse conv, MFMA core ------------------------------------------------
// Tile 128(pairs) x 128(cout), BK=64, 4 waves each computing 64x64 via 4x4
// 16x16x32 bf16 MFMA fragments.  USEMAP=false: center offset (k=13, identity
// map), plain stores (doubles as accumulator init).  USEMAP=true: 26
// off-center offsets, gather in_map / scatter atomicAdd, sentinel out==n_out
// masks padded pairs; all-invalid tiles early-exit (pairs are prefix-packed).
template<bool USEMAP>
__global__ __launch_bounds__(256) void conv_mfma(
    const ushort* __restrict__ x, const ushort* __restrict__ wT,
    const int* __restrict__ in_map, const int* __restrict__ out_map,
    float* __restrict__ out, int P, int n_out, int C_in)
{
  const int k  = USEMAP ? ((int)blockIdx.z + (blockIdx.z >= 13 ? 1 : 0)) : 13;
  const int p0 = blockIdx.x * 128;
  const int j0 = blockIdx.y * 128;
  const int t  = threadIdx.x;

  __shared__ int out_s[128];
  __shared__ int in_s[128];
  __shared__ int anyv;

  if (USEMAP) {
    if (t == 0) anyv = 0;
    __syncthreads();
    if (t < 128) {
      int p  = p0 + t;
      int oi = (p < P) ? out_map[(size_t)k * P + p] : n_out;
      int ii = (p < P) ? in_map[(size_t)k * P + p]  : 0;
      out_s[t] = oi; in_s[t] = ii;
      if (oi < n_out) anyv = 1;       // benign race
    }
    __syncthreads();
    if (!anyv) return;                // block-uniform
  } else {
    if (t < 128) {
      int p = p0 + t;
      out_s[t] = p;
      in_s[t]  = (p < n_out) ? p : 0;
    }
    __syncthreads();
  }

  // pitch 72 bf16 = 144 B: 16B-aligned b128, rows spread across banks
  __shared__ ushort A_s[128][72];
  __shared__ ushort B_s[128][72];

  const int lr = t >> 3;              // loader row base 0..31
  const int lo = (t & 7) * 8;         // loader k offset (elements)
  const ushort* wk = wT + ((size_t)k * CMID + j0) * C_in;

  const ushort* asrc[4]; const ushort* bsrc[4];
  ushort* adst[4]; ushort* bdst[4];
#pragma unroll
  for (int i = 0; i < 4; ++i) {
    int row = lr + 32 * i;
    asrc[i] = x  + (size_t)in_s[row] * C_in + lo;
    bsrc[i] = wk + (size_t)row       * C_in + lo;
    adst[i] = &A_s[row][lo];
    bdst[i] = &B_s[row][lo];
  }

  const int lane = t & 63;
  const int wv   = t >> 6;
  const int wm   = (wv & 1) * 64;
  const int wn   = (wv >> 1) * 64;
  const int ml   = lane & 15;
  const int q    = lane >> 4;

  f32x4 acc[4][4] = {};

  for (int kb = 0; kb < C_in; kb += 64) {
#pragma unroll
    for (int i = 0; i < 4; ++i) {
      *(uint4*)adst[i] = *(const uint4*)(asrc[i] + kb);
      *(uint4*)bdst[i] = *(const uint4*)(bsrc[i] + kb);
    }
    __syncthreads();
#pragma unroll
    for (int ks = 0; ks < 2; ++ks) {
      bf16x8 af[4], bb[4];
#pragma unroll
      for (int mt = 0; mt < 4; ++mt)
        af[mt] = *(const bf16x8*)&A_s[wm + mt * 16 + ml][ks * 32 + q * 8];
#pragma unroll
      for (int nt = 0; nt < 4; ++nt)
        bb[nt] = *(const bf16x8*)&B_s[wn + nt * 16 + ml][ks * 32 + q * 8];
#pragma unroll
      for (int mt = 0; mt < 4; ++mt)
#pragma unroll
        for (int nt = 0; nt < 4; ++nt)
          acc[mt][nt] = __builtin_amdgcn_mfma_f32_16x16x32_bf16(
              af[mt], bb[nt], acc[mt][nt], 0, 0, 0);
    }
    __syncthreads();
  }

  // C/D layout: col = lane&15, row = (lane>>4)*4 + reg   [m89-verified]
#pragma unroll
  for (int mt = 0; mt < 4; ++mt) {
#pragma unroll
    for (int r = 0; r < 4; ++r) {
      int o = out_s[wm + mt * 16 + q * 4 + r];
      if (o < n_out) {
        float* orow = out + (size_t)o * CMID + j0 + wn + ml;
#pragma unroll
        for (int nt = 0; nt < 4; ++nt) {
          if (USEMAP) atomicAdd(orow + nt * 16, acc[mt][nt][r]);
          else        orow[nt * 16] = acc[mt][nt][r];
        }
      }
    }
  }
}

// ---- BN stats (fp32 accum buffer) -----------------------------------------
__global__ __launch_bounds__(256) void bn_stats_kernel(
    const float* __restrict__ x, float* __restrict__ stats, int n)
{
  int t = threadIdx.x;
  float s0 = 0.f, q0 = 0.f, s1 = 0.f, q1 = 0.f;
  for (int r = blockIdx.x; r < n; r += gridDim.x) {
    const float* row = x + (size_t)r * CMID;
    float v0 = row[t];
    float v1 = row[t + 256];
    s0 += v0; q0 += v0 * v0;
    s1 += v1; q1 += v1 * v1;
  }
  atomicAdd(&stats[t],        s0);
  atomicAdd(&stats[512 + t],  q0);
  atomicAdd(&stats[t + 256],  s1);
  atomicAdd(&stats[768 + t],  q1);
}

// ---- BN apply + ReLU, fp32 in -> bf16 out ---------------------------------
__global__ __launch_bounds__(256) void bn_apply_cast(
    const float* __restrict__ x, const float* __restrict__ stats,
    const float* __restrict__ gamma, const float* __restrict__ beta,
    ushort* __restrict__ y, long total, float inv_n)
{
  long i = (long)blockIdx.x * 256 + threadIdx.x;
  if (i >= total) return;
  int c = (int)(i & 511);
  float mu  = stats[c] * inv_n;
  float var = stats[512 + c] * inv_n - mu * mu;
  float g   = gamma[c] * rsqrtf(var + 1e-5f);
  float v   = (x[i] - mu) * g + beta[c];
  y[i] = f2bf(v > 0.f ? v : 0.f);
}

// ---- pools (values post-ReLU >= 0 -> int-punned atomicMax) ----------------
__global__ __launch_bounds__(256) void pool_max_bf16(
    const ushort* __restrict__ x, const int* __restrict__ idx,
    float* __restrict__ out, long total)
{
  long i = (long)blockIdx.x * 256 + threadIdx.x;
  if (i >= total) return;
  int r = (int)(i >> 9);
  int c = (int)(i & 511);
  int o = idx[r];
  int bits = ((int)x[i]) << 16;     // bf16 -> fp32 bits (>= 0)
  atomicMax((int*)(out + (size_t)o * CMID + c), bits);
}

__global__ __launch_bounds__(256) void pool_max_f32(
    const float* __restrict__ x, const int* __restrict__ idx,
    float* __restrict__ out, long total)
{
  long i = (long)blockIdx.x * 256 + threadIdx.x;
  if (i >= total) return;
  int r = (int)(i >> 9);
  int c = (int)(i & 511);
  int o = idx[r];
  atomicMax((int*)(out + (size_t)o * CMID + c), __float_as_int(x[i]));
}

// ---- cast fp32 -> bf16 -----------------------------------------------------
__global__ __launch_bounds__(256) void cast_f32_bf16_kernel(
    const float* __restrict__ in, ushort* __restrict__ out, long n)
{
  long i = (long)blockIdx.x * 256 + threadIdx.x;
  if (i < n) out[i] = f2bf(in[i]);
}

// ---- FC: partial GEMM with K-split, h += x[8][Kc] @ W[Kc][N] --------------
// grid (N/64, KS), block 256 = 64 j x 4 batch-groups (2 batches each)
__global__ __launch_bounds__(256) void fc_partial(
    const float* __restrict__ x, const float* __restrict__ W,
    float* __restrict__ h, int K, int N, int Kc)
{
  __shared__ float xs[8][1024];
  int t  = threadIdx.x;
  int j  = blockIdx.x * 64 + (t & 63);
  int bg = t >> 6;
  int k0 = blockIdx.y * Kc;
  for (int i = t; i < 8 * Kc; i += 256) {
    int b = i / Kc; int kk = i - b * Kc;
    xs[b][kk] = x[(size_t)b * K + k0 + kk];
  }
  __syncthreads();
  float a0 = 0.f, a1 = 0.f;
  for (int kk = 0; kk < Kc; ++kk) {
    float wv = W[(size_t)(k0 + kk) * N + j];
    a0 += xs[bg][kk] * wv;
    a1 += xs[bg + 4][kk] * wv;
  }
  atomicAdd(&h[(size_t)bg * N + j], a0);
  atomicAdd(&h[(size_t)(bg + 4) * N + j], a1);
}

__global__ __launch_bounds__(256) void bias_relu_kernel(
    float* __restrict__ h, const float* __restrict__ bias, int N)
{
  int i = blockIdx.x * 256 + threadIdx.x;
  if (i >= 8 * N) return;
  float v = h[i] + bias[i % N];
  h[i] = v > 0.f ? v : 0.f;
}

// ---- FC3: [8,4096] @ [4096,40] + b ----------------------------------------
__global__ __launch_bounds__(320) void fc3_kernel(
    const float* __restrict__ x, const float* __restrict__ W,
    const float* __restrict__ bias, float* __restrict__ out)
{
  int t = threadIdx.x;
  int j = t % 40;
  int b = t / 40;
  int kb = blockIdx.x * 128;
  float acc = 0.f;
#pragma unroll 8
  for (int kk = 0; kk < 128; ++kk)
    acc += x[(size_t)b * 4096 + kb + kk] * W[(size_t)(kb + kk) * 40 + j];
  if (blockIdx.x == 0) acc += bias[j];
  atomicAdd(&out[(size_t)b * 40 + j], acc);
}

// ---------------------------------------------------------------------------
extern "C" void kernel_launch(void* const* d_in, const int* in_sizes, int n_in,
                              void* d_out, int out_size, void* d_ws, size_t ws_size,
                              hipStream_t stream)
{
  const float* feats  = (const float*)d_in[0];
  const float* wts[6] = {(const float*)d_in[1], (const float*)d_in[2],
                         (const float*)d_in[3], (const float*)d_in[4],
                         (const float*)d_in[5], (const float*)d_in[6]};
  const float* bn_g   = (const float*)d_in[7];
  const float* bn_b   = (const float*)d_in[8];
  const float* fc1_w  = (const float*)d_in[9];
  const float* fc1_b  = (const float*)d_in[10];
  const float* fc2_w  = (const float*)d_in[11];
  const float* fc2_b  = (const float*)d_in[12];
  const float* fc3_w  = (const float*)d_in[13];
  const float* fc3_b  = (const float*)d_in[14];
  const int* map1_in  = (const int*)d_in[15];
  const int* map1_out = (const int*)d_in[16];
  const int* map2_in  = (const int*)d_in[17];
  const int* map2_out = (const int*)d_in[18];
  const int* pool1_idx = (const int*)d_in[19];
  const int* pool2_idx = (const int*)d_in[20];
  const int* batch_idx = (const int*)d_in[21];

  const int N1 = in_sizes[0] / 256;
  const int P1 = in_sizes[15] / 27;
  const int P2 = in_sizes[17] / 27;
  const int n2 = in_sizes[20];
  const int n3 = in_sizes[21];

  // workspace layout (~126.3 MiB; round-1 proved ws >= 128 MiB):
  const size_t MB = (size_t)1 << 20;
  char* wsb = (char*)d_ws;
  float*  accum   = (float*)wsb;                 // 64 MiB fp32 conv accum / pool1 fp32
  ushort* fbuf    = (ushort*)(wsb + 64 * MB);    // 32 MiB bf16 features (ping in-place)
  ushort* featsb  = (ushort*)(wsb + 96 * MB);    // 16 MiB bf16 conv1 input, later pooled2f
  ushort* wTbuf   = (ushort*)(wsb + 112 * MB);   // 13.5 MiB bf16 transposed weights
  float*  stats   = (float*)(wsb + 126 * MB);    // 1024 f
  float*  gpooled = stats + 1024;                // [8][512]
  float*  h1      = gpooled + 8 * 512;           // [8][4096]
  float*  h2      = h1 + 8 * 4096;               // [8][4096]
  float*  pooled2f = (float*)featsb;             // n3*512 fp32

  long nf = (long)N1 * 256;
  cast_f32_bf16_kernel<<<(int)((nf + 255) / 256), 256, 0, stream>>>(feats, featsb, nf);

  auto conv = [&](const ushort* xin, const float* w, const int* mi, const int* mo,
                  int P, int nout, int Cin) {
    transpose_w_kernel<<<dim3(Cin / 32, CMID / 32, 27), 256, 0, stream>>>(w, wTbuf, Cin);
    conv_mfma<false><<<dim3((nout + 127) / 128, 4, 1), 256, 0, stream>>>(
        xin, wTbuf, nullptr, nullptr, accum, P, nout, Cin);
    conv_mfma<true><<<dim3((P + 127) / 128, 4, 26), 256, 0, stream>>>(
        xin, wTbuf, mi, mo, accum, P, nout, Cin);
  };
  auto bn = [&](int layer, int n) {
    hipMemsetAsync(stats, 0, 1024 * sizeof(float), stream);
    bn_stats_kernel<<<256, 256, 0, stream>>>(accum, stats, n);
    long tot = (long)n * CMID;
    bn_apply_cast<<<(int)((tot + 255) / 256), 256, 0, stream>>>(
        accum, stats, bn_g + layer * CMID, bn_b + layer * CMID, fbuf, tot, 1.0f / n);
  };

  // --- level 1 ---
  conv(featsb, wts[0], map1_in, map1_out, P1, N1, 256); bn(0, N1);
  conv(fbuf,   wts[1], map1_in, map1_out, P1, N1, 512); bn(1, N1);
  conv(fbuf,   wts[2], map1_in, map1_out, P1, N1, 512); bn(2, N1);

  // --- pool 1 ---
  long t1 = (long)N1 * CMID;
  long t2 = (long)n2 * CMID;
  hipMemsetAsync(accum, 0, (size_t)n2 * CMID * sizeof(float), stream);
  pool_max_bf16<<<(int)((t1 + 255) / 256), 256, 0, stream>>>(fbuf, pool1_idx, accum, t1);
  cast_f32_bf16_kernel<<<(int)((t2 + 255) / 256), 256, 0, stream>>>(accum, fbuf, t2);

  // --- level 2 ---
  conv(fbuf, wts[3], map2_in, map2_out, P2, n2, 512); bn(3, n2);
  conv(fbuf, wts[4], map2_in, map2_out, P2, n2, 512); bn(4, n2);
  conv(fbuf, wts[5], map2_in, map2_out, P2, n2, 512); bn(5, n2);

  // --- pool 2 + global max pool ---
  long t3 = (long)n3 * CMID;
  hipMemsetAsync(pooled2f, 0, (size_t)n3 * CMID * sizeof(float), stream);
  pool_max_bf16<<<(int)((t2 + 255) / 256), 256, 0, stream>>>(fbuf, pool2_idx, pooled2f, t2);
  hipMemsetAsync(gpooled, 0, 8 * CMID * sizeof(float), stream);
  pool_max_f32<<<(int)((t3 + 255) / 256), 256, 0, stream>>>(pooled2f, batch_idx, gpooled, t3);

  // --- FC head ---
  hipMemsetAsync(h1, 0, 8 * 4096 * sizeof(float), stream);
  fc_partial<<<dim3(64, 1), 256, 0, stream>>>(gpooled, fc1_w, h1, 512, 4096, 512);
  bias_relu_kernel<<<128, 256, 0, stream>>>(h1, fc1_b, 4096);
  hipMemsetAsync(h2, 0, 8 * 4096 * sizeof(float), stream);
  fc_partial<<<dim3(64, 4), 256, 0, stream>>>(h1, fc2_w, h2, 4096, 4096, 1024);
  bias_relu_kernel<<<128, 256, 0, stream>>>(h2, fc2_b, 4096);
  hipMemsetAsync(d_out, 0, (size_t)out_size * sizeof(float), stream);
  fc3_kernel<<<32, 320, 0, stream>>>(h2, fc3_w, fc3_b, (float*)d_out);
}